// Round 4
// baseline (17725.266 us; speedup 1.0000x reference)
//
#include <hip/hip_runtime.h>
#include <math.h>

#define BB 64
#define TT 128
#define EE 1024
#define DD 1024
#define VV 10000
#define G4 4096  // 4*D

typedef float f32x4 __attribute__((ext_vector_type(4)));
typedef __bf16 bf16x8 __attribute__((ext_vector_type(8)));

__device__ __forceinline__ unsigned short f2bf(float f) {
    unsigned int u = __float_as_uint(f);
    return (unsigned short)((u + 0x7fffu + ((u >> 16) & 1u)) >> 16);  // RNE
}

__device__ __forceinline__ void gload_lds16(const void* g, void* l) {
    __builtin_amdgcn_global_load_lds((const __attribute__((address_space(1))) void*)g,
                                     (__attribute__((address_space(3))) void*)l, 16, 0, 0);
}

// ---------------- Kernel 1: stable descending argsort of lengths ----------------
__global__ void sort_kernel(const int* __restrict__ lens_raw,
                            int* __restrict__ sort_ind,
                            int* __restrict__ dec_len) {
    // single thread; 64 elements. int64-vs-int32 autodetect: lens in [2,128],
    // so if buffer is int64 LE, word 1 (high word of lens[0]) is 0.
    int stride = (lens_raw[1] == 0) ? 2 : 1;
    int lens[BB], idx[BB];
    for (int i = 0; i < BB; ++i) { lens[i] = lens_raw[i * stride]; idx[i] = i; }
    for (int i = 1; i < BB; ++i) {  // stable insertion sort, descending
        int kl = lens[i], ki = idx[i];
        int j = i - 1;
        while (j >= 0 && lens[j] < kl) { lens[j+1] = lens[j]; idx[j+1] = idx[j]; --j; }
        lens[j+1] = kl; idx[j+1] = ki;
    }
    for (int i = 0; i < BB; ++i) { sort_ind[i] = idx[i]; dec_len[i] = lens[i] - 1; }
}

// ---------------- Kernel 2: W_fc f32 -> bf16 ----------------
__global__ __launch_bounds__(256) void cvt_wfc(const float* __restrict__ w,
                                               unsigned short* __restrict__ o) {
    const int i = (blockIdx.x * 256 + threadIdx.x) * 4;
    if (i + 3 < VV * DD) {
        float4 v = *(const float4*)(w + i);
        ushort4 r;
        r.x = f2bf(v.x); r.y = f2bf(v.y); r.z = f2bf(v.z); r.w = f2bf(v.w);
        *(ushort4*)(o + i) = r;
    }
}

// ---------------- Kernel 3: f32 GEMM  X = enc_sorted @ W_ih^T + b_ih + b_hh ----
// M = 8192 rows (r = t*64 + b), N = 4096, K = 1024. A gathered via sort_ind.
#define TM 64
#define TN 64
#define TK 16

__global__ __launch_bounds__(256) void gemm_x(const float* __restrict__ enc,
                                              const float* __restrict__ Wih,
                                              const float* __restrict__ bih,
                                              const float* __restrict__ bhh,
                                              const int* __restrict__ sind,
                                              float* __restrict__ X) {
    __shared__ __align__(16) float As[TK][TM + 4];
    __shared__ __align__(16) float Bs[TK][TN + 4];
    const int tid = threadIdx.x;
    const int m0 = blockIdx.y * TM;
    const int n0 = blockIdx.x * TN;
    const int lr = tid >> 2;           // 0..63: row within tile (loads)
    const int lk = (tid & 3) * 4;      // 0,4,8,12: k offset (float4)
    const int r = m0 + lr;
    const int t = r >> 6, b = r & 63;
    const float* arow = enc + ((size_t)sind[b] * TT + t) * EE;
    const float* brow = Wih + (size_t)(n0 + lr) * EE;
    const int tx = tid & 15, ty = tid >> 4;
    float acc[4][4] = {};
    for (int k0 = 0; k0 < EE; k0 += TK) {
        float4 av = *(const float4*)(arow + k0 + lk);
        float4 bv = *(const float4*)(brow + k0 + lk);
        __syncthreads();
        As[lk+0][lr] = av.x; As[lk+1][lr] = av.y; As[lk+2][lr] = av.z; As[lk+3][lr] = av.w;
        Bs[lk+0][lr] = bv.x; Bs[lk+1][lr] = bv.y; Bs[lk+2][lr] = bv.z; Bs[lk+3][lr] = bv.w;
        __syncthreads();
#pragma unroll
        for (int k = 0; k < TK; ++k) {
            float4 a = *(const float4*)&As[k][ty * 4];
            float4 bq = *(const float4*)&Bs[k][tx * 4];
            float ar[4] = {a.x, a.y, a.z, a.w};
            float br[4] = {bq.x, bq.y, bq.z, bq.w};
#pragma unroll
            for (int i = 0; i < 4; ++i)
#pragma unroll
                for (int j = 0; j < 4; ++j) acc[i][j] += ar[i] * br[j];
        }
    }
#pragma unroll
    for (int i = 0; i < 4; ++i) {
        const int rr = m0 + ty * 4 + i;
#pragma unroll
        for (int j = 0; j < 4; ++j) {
            const int cc = n0 + tx * 4 + j;
            X[(size_t)rr * G4 + cc] = acc[i][j] + bih[cc] + bhh[cc];
        }
    }
}

// ---------------- Kernel 4: one LSTM step (f32, fused gates + elementwise) ------
// grid.x = 256 (d-chunks of 4), block = 256: thread -> (b = tid>>2, dl = tid&3)
// hall written as bf16 in (b, t, d) layout for the MFMA FC head.
__global__ __launch_bounds__(256) void step_kernel(const float* __restrict__ X,
                                                   const float* __restrict__ Whh,
                                                   const float* __restrict__ hp,
                                                   float* __restrict__ hn,
                                                   float* __restrict__ c,
                                                   const int* __restrict__ declen,
                                                   unsigned short* __restrict__ hall,
                                                   int t) {
    const int tid = threadIdx.x;
    const int b = tid >> 2;
    const int d = blockIdx.x * 4 + (tid & 3);
    const float* Xt = X + ((size_t)t * BB + b) * G4;
    float acc0 = Xt[d];
    float acc1 = Xt[DD + d];
    float acc2 = Xt[2 * DD + d];
    float acc3 = Xt[3 * DD + d];
    const float4* h4 = (const float4*)(hp + (size_t)b * DD);
    const float4* w0 = (const float4*)(Whh + (size_t)d * DD);
    const float4* w1 = (const float4*)(Whh + (size_t)(DD + d) * DD);
    const float4* w2 = (const float4*)(Whh + (size_t)(2 * DD + d) * DD);
    const float4* w3 = (const float4*)(Whh + (size_t)(3 * DD + d) * DD);
#pragma unroll 4
    for (int k = 0; k < DD / 4; ++k) {
        float4 hv = h4[k];
        float4 a = w0[k];
        acc0 += hv.x * a.x + hv.y * a.y + hv.z * a.z + hv.w * a.w;
        float4 f4 = w1[k];
        acc1 += hv.x * f4.x + hv.y * f4.y + hv.z * f4.z + hv.w * f4.w;
        float4 g4 = w2[k];
        acc2 += hv.x * g4.x + hv.y * g4.y + hv.z * g4.z + hv.w * g4.w;
        float4 o4 = w3[k];
        acc3 += hv.x * o4.x + hv.y * o4.y + hv.z * o4.z + hv.w * o4.w;
    }
    const float ig = 1.0f / (1.0f + expf(-acc0));
    const float fg = 1.0f / (1.0f + expf(-acc1));
    const float gg = tanhf(acc2);
    const float og = 1.0f / (1.0f + expf(-acc3));
    const size_t bd = (size_t)b * DD + d;
    const float cold = c[bd];
    const float cnew = fg * cold + ig * gg;
    const float hnew = og * tanhf(cnew);
    const float hold = hp[bd];
    const bool active = t < declen[b];
    const float hout = active ? hnew : hold;
    c[bd] = active ? cnew : cold;
    hn[bd] = hout;
    hall[((size_t)b * TT + t) * DD + d] = f2bf(hout);   // (b,t,d): row r = b*128+t
}

// ---------------- Kernel 5: bf16 MFMA FC head: out = hall @ Wfc^T + b_fc -------
// M = 8192 (row r = b*128+t, matches output), N = 10000 (guarded), K = 1024.
// m97 structure: 128x128 tile, BK=64, 4 waves (2x2 of 64x64), global_load_lds w16.
#define FBM 128
#define FBN 128
#define FBK 64

__global__ __launch_bounds__(256) void gemm_fc_mfma(const __bf16* __restrict__ A,
                                                    const __bf16* __restrict__ Bw,
                                                    const float* __restrict__ bfc,
                                                    float* __restrict__ out) {
    __shared__ __align__(16) __bf16 As[FBM * FBK];   // 16 KB, rows m, linear
    __shared__ __align__(16) __bf16 Bs[FBN * FBK];   // 16 KB, rows n, linear
    const int tid = threadIdx.x;
    const int lane = tid & 63;
    const int wave = tid >> 6;
    const int m0 = blockIdx.y * FBM;
    const int n0 = blockIdx.x * FBN;
    const int wm = (wave & 1) * 64;
    const int wn = (wave >> 1) * 64;
    const int fr = lane & 15;    // fragment row (A) / col (B,D)
    const int fq = lane >> 4;    // k-quad
    f32x4 acc[4][4] = {};
    for (int k0 = 0; k0 < DD; k0 += FBK) {
        __syncthreads();  // previous iteration's readers done
#pragma unroll
        for (int i = 0; i < 4; ++i) {
            const int e = tid * 8 + i * 2048;     // flat element in 128x64 tile
            const int row = e >> 6, col = e & 63;
            gload_lds16(A + (size_t)(m0 + row) * DD + k0 + col, &As[e]);
            int bn = n0 + row; if (bn >= VV) bn = VV - 1;
            gload_lds16(Bw + (size_t)bn * DD + k0 + col, &Bs[e]);
        }
        __syncthreads();  // drains vmcnt(0): tiles resident
#pragma unroll
        for (int ks = 0; ks < 2; ++ks) {
            bf16x8 af[4], bfg[4];
#pragma unroll
            for (int mi = 0; mi < 4; ++mi)
                af[mi] = *(const bf16x8*)&As[(wm + mi * 16 + fr) * FBK + ks * 32 + fq * 8];
#pragma unroll
            for (int ni = 0; ni < 4; ++ni)
                bfg[ni] = *(const bf16x8*)&Bs[(wn + ni * 16 + fr) * FBK + ks * 32 + fq * 8];
#pragma unroll
            for (int mi = 0; mi < 4; ++mi)
#pragma unroll
                for (int ni = 0; ni < 4; ++ni)
                    acc[mi][ni] = __builtin_amdgcn_mfma_f32_16x16x32_bf16(
                        af[mi], bfg[ni], acc[mi][ni], 0, 0, 0);
        }
    }
    // C/D layout (m89-verified): col = lane&15, row = (lane>>4)*4 + reg
#pragma unroll
    for (int mi = 0; mi < 4; ++mi)
#pragma unroll
        for (int ni = 0; ni < 4; ++ni) {
            const int col = n0 + wn + ni * 16 + fr;
            if (col < VV) {
                const float bias = bfc[col];
#pragma unroll
                for (int rg = 0; rg < 4; ++rg) {
                    const int row = m0 + wm + mi * 16 + fq * 4 + rg;
                    out[(size_t)row * VV + col] = acc[mi][ni][rg] + bias;
                }
            }
        }
}

// ---------------- launch ----------------
extern "C" void kernel_launch(void* const* d_in, const int* in_sizes, int n_in,
                              void* d_out, int out_size, void* d_ws, size_t ws_size,
                              hipStream_t stream) {
    const float* enc = (const float*)d_in[0];
    const int* capl = (const int*)d_in[1];
    const float* Wih = (const float*)d_in[2];
    const float* bih = (const float*)d_in[3];
    const float* Whh = (const float*)d_in[4];
    const float* bhh = (const float*)d_in[5];
    const float* Wfc = (const float*)d_in[6];
    const float* bfc = (const float*)d_in[7];
    float* out = (float*)d_out;

    char* ws = (char*)d_ws;
    int* sind = (int*)(ws + 0);
    int* declen = (int*)(ws + 256);
    float* h0 = (float*)(ws + 4096);
    float* h1 = h0 + (size_t)BB * DD;
    float* c = h1 + (size_t)BB * DD;
    float* X = c + (size_t)BB * DD;                          // 8192*4096 f32 = 134.2 MB
    unsigned short* hallb = (unsigned short*)(X + (size_t)BB * TT * G4);  // 16.8 MB
    unsigned short* wfcb = hallb + (size_t)BB * TT * DD;                  // 20.5 MB

    hipMemsetAsync(h0, 0, (size_t)BB * DD * sizeof(float), stream);
    hipMemsetAsync(c, 0, (size_t)BB * DD * sizeof(float), stream);

    sort_kernel<<<1, 1, 0, stream>>>(capl, sind, declen);
    cvt_wfc<<<(VV * DD) / 1024, 256, 0, stream>>>(Wfc, wfcb);

    gemm_x<<<dim3(G4 / TN, (BB * TT) / TM), 256, 0, stream>>>(enc, Wih, bih, bhh, sind, X);

    for (int t = 0; t < TT; ++t) {
        const float* hp = (t & 1) ? h1 : h0;
        float* hn = (t & 1) ? h0 : h1;
        step_kernel<<<256, 256, 0, stream>>>(X, Whh, hp, hn, c, declen, hallb, t);
    }

    gemm_fc_mfma<<<dim3((VV + FBN - 1) / FBN, (BB * TT) / FBM), 256, 0, stream>>>(
        (const __bf16*)hallb, (const __bf16*)wfcb, bfc, out);
}

// Round 6
// 4790.472 us; speedup vs baseline: 3.7001x; 3.7001x over previous
//
#include <hip/hip_runtime.h>
#include <math.h>

#define BB 64
#define TT 128
#define EE 1024
#define DD 1024
#define VV 10000
#define G4 4096  // 4*D
#define NBLK 64  // recurrence workgroups (all co-resident on 256 CUs)

typedef float f32x4 __attribute__((ext_vector_type(4)));
typedef __bf16 bf16x8 __attribute__((ext_vector_type(8)));

__device__ __forceinline__ unsigned short f2bf(float f) {
    unsigned int u = __float_as_uint(f);
    return (unsigned short)((u + 0x7fffu + ((u >> 16) & 1u)) >> 16);  // RNE
}

__device__ __forceinline__ void gload_lds16(const void* g, void* l) {
    __builtin_amdgcn_global_load_lds((const __attribute__((address_space(1))) void*)g,
                                     (__attribute__((address_space(3))) void*)l, 16, 0, 0);
}

// Device-scope sense-reversing grid barrier (cross-XCD safe: AGENT-scope atomics).
__device__ __forceinline__ void grid_barrier(int* cnt, int* gen, int nblocks) {
    __syncthreads();
    if (threadIdx.x == 0) {
        __threadfence();  // flush this block's global writes (device scope)
        int g = __hip_atomic_load(gen, __ATOMIC_RELAXED, __HIP_MEMORY_SCOPE_AGENT);
        int a = __hip_atomic_fetch_add(cnt, 1, __ATOMIC_ACQ_REL, __HIP_MEMORY_SCOPE_AGENT);
        if (a == nblocks - 1) {
            __hip_atomic_store(cnt, 0, __ATOMIC_RELAXED, __HIP_MEMORY_SCOPE_AGENT);
            __hip_atomic_fetch_add(gen, 1, __ATOMIC_ACQ_REL, __HIP_MEMORY_SCOPE_AGENT);
        } else {
            while (__hip_atomic_load(gen, __ATOMIC_ACQUIRE, __HIP_MEMORY_SCOPE_AGENT) == g)
                __builtin_amdgcn_s_sleep(1);
        }
    }
    __syncthreads();
}

// ---------------- Kernel 1: stable descending argsort of lengths ----------------
__global__ void sort_kernel(const int* __restrict__ lens_raw,
                            int* __restrict__ sort_ind,
                            int* __restrict__ dec_len) {
    // single thread; 64 elements. int64-vs-int32 autodetect: lens in [2,128],
    // so if buffer is int64 LE, word 1 (high word of lens[0]) is 0.
    int stride = (lens_raw[1] == 0) ? 2 : 1;
    int lens[BB], idx[BB];
    for (int i = 0; i < BB; ++i) { lens[i] = lens_raw[i * stride]; idx[i] = i; }
    for (int i = 1; i < BB; ++i) {  // stable insertion sort, descending
        int kl = lens[i], ki = idx[i];
        int j = i - 1;
        while (j >= 0 && lens[j] < kl) { lens[j+1] = lens[j]; idx[j+1] = idx[j]; --j; }
        lens[j+1] = kl; idx[j+1] = ki;
    }
    for (int i = 0; i < BB; ++i) { sort_ind[i] = idx[i]; dec_len[i] = lens[i] - 1; }
}

// ---------------- Kernel 2: f32 -> bf16 convert (W_fc, W_hh) ----------------
__global__ __launch_bounds__(256) void cvt_bf16(const float* __restrict__ w,
                                                unsigned short* __restrict__ o, int n) {
    const int i = (blockIdx.x * 256 + threadIdx.x) * 4;
    if (i + 3 < n) {
        float4 v = *(const float4*)(w + i);
        ushort4 r;
        r.x = f2bf(v.x); r.y = f2bf(v.y); r.z = f2bf(v.z); r.w = f2bf(v.w);
        *(ushort4*)(o + i) = r;
    }
}

// ---------------- Kernel 3: f32 GEMM  X = enc_sorted @ W_ih^T + b_ih + b_hh ----
// M = 8192 rows (r = t*64 + b), N = 4096, K = 1024. A gathered via sort_ind.
// Stores TRANSPOSED: XT[(t*4096 + gate_row)*64 + b] for the recurrence kernel.
#define TM 64
#define TN 64
#define TK 16

__global__ __launch_bounds__(256) void gemm_x(const float* __restrict__ enc,
                                              const float* __restrict__ Wih,
                                              const float* __restrict__ bih,
                                              const float* __restrict__ bhh,
                                              const int* __restrict__ sind,
                                              float* __restrict__ XT) {
    __shared__ __align__(16) float As[TK][TM + 4];
    __shared__ __align__(16) float Bs[TK][TN + 4];
    const int tid = threadIdx.x;
    const int m0 = blockIdx.y * TM;     // one full t per block (TM == BB)
    const int n0 = blockIdx.x * TN;
    const int lr = tid >> 2;
    const int lk = (tid & 3) * 4;
    const int r = m0 + lr;
    const int t = r >> 6, b = r & 63;
    const float* arow = enc + ((size_t)sind[b] * TT + t) * EE;
    const float* brow = Wih + (size_t)(n0 + lr) * EE;
    const int tx = tid & 15, ty = tid >> 4;
    float acc[4][4] = {};
    for (int k0 = 0; k0 < EE; k0 += TK) {
        float4 av = *(const float4*)(arow + k0 + lk);
        float4 bv = *(const float4*)(brow + k0 + lk);
        __syncthreads();
        As[lk+0][lr] = av.x; As[lk+1][lr] = av.y; As[lk+2][lr] = av.z; As[lk+3][lr] = av.w;
        Bs[lk+0][lr] = bv.x; Bs[lk+1][lr] = bv.y; Bs[lk+2][lr] = bv.z; Bs[lk+3][lr] = bv.w;
        __syncthreads();
#pragma unroll
        for (int k = 0; k < TK; ++k) {
            float4 a = *(const float4*)&As[k][ty * 4];
            float4 bq = *(const float4*)&Bs[k][tx * 4];
            float ar[4] = {a.x, a.y, a.z, a.w};
            float br[4] = {bq.x, bq.y, bq.z, bq.w};
#pragma unroll
            for (int i = 0; i < 4; ++i)
#pragma unroll
                for (int j = 0; j < 4; ++j) acc[i][j] += ar[i] * br[j];
        }
    }
    const int tb = m0 >> 6;  // t index for this block
#pragma unroll
    for (int i = 0; i < 4; ++i) {
        const int bb = ty * 4 + i;  // batch row within tile (== r & 63)
#pragma unroll
        for (int j = 0; j < 4; ++j) {
            const int cc = n0 + tx * 4 + j;
            XT[((size_t)tb * G4 + cc) * 64 + bb] = acc[i][j] + bih[cc] + bhh[cc];
        }
    }
}

// ---------------- Kernel 4: persistent fused LSTM recurrence --------------------
// 64 blocks x 256 threads; block j owns d-slice [j*16, j*16+16) -> 64 gate rows
// (4 gates x 16). Per step: MFMA GEMV h@Whh^T (bf16, operands straight from
// L2-hot global), += XT, gate math (c lives in LDS), write h (dbuf) + hall,
// grid barrier. One launch replaces 128 step-kernel launches.
__global__ __launch_bounds__(256) void recurrence(const __bf16* __restrict__ Whhb,
                                                  const float* __restrict__ XT,
                                                  const int* __restrict__ declen,
                                                  __bf16* __restrict__ H0,
                                                  __bf16* __restrict__ H1,
                                                  unsigned short* __restrict__ hall,
                                                  int* __restrict__ bcnt,
                                                  int* __restrict__ bgen) {
    __shared__ float gl[64][65];     // [n_local][b] gate pre-activations
    __shared__ float c_s[16][65];    // [dl][b] cell state (persistent across steps)
    __shared__ int dlen_s[BB];
    const int tid = threadIdx.x;
    const int j = blockIdx.x;
    const int lane = tid & 63;
    const int wave = tid >> 6;
    const int wm = (wave & 1) * 32;   // batch sub-range
    const int wn = (wave >> 1) * 32;  // gate-row sub-range
    const int fr = lane & 15;
    const int fq = lane >> 4;

    if (tid < BB) dlen_s[tid] = declen[tid];
    for (int i = tid; i < 16 * 65; i += 256) (&c_s[0][0])[i] = 0.f;
    __syncthreads();

    // B-operand rows: global gate row = g*1024 + j*16 + fr, g = wn/16 + ni
    const __bf16* wrow0 = Whhb + ((size_t)((wn >> 4) + 0) * DD + j * 16 + fr) * DD;
    const __bf16* wrow1 = Whhb + ((size_t)((wn >> 4) + 1) * DD + j * 16 + fr) * DD;

    for (int t = 0; t < TT; ++t) {
        const __bf16* Hp = (t & 1) ? H1 : H0;
        __bf16* Hn = (t & 1) ? H0 : H1;
        const __bf16* arow0 = Hp + (size_t)(wm + fr) * DD;
        const __bf16* arow1 = Hp + (size_t)(wm + 16 + fr) * DD;
        f32x4 acc[2][2] = {};
#pragma unroll 4
        for (int k0 = 0; k0 < DD; k0 += 32) {
            const int ko = k0 + fq * 8;
            bf16x8 a0 = *(const bf16x8*)(arow0 + ko);
            bf16x8 a1 = *(const bf16x8*)(arow1 + ko);
            bf16x8 b0 = *(const bf16x8*)(wrow0 + ko);
            bf16x8 b1 = *(const bf16x8*)(wrow1 + ko);
            acc[0][0] = __builtin_amdgcn_mfma_f32_16x16x32_bf16(a0, b0, acc[0][0], 0, 0, 0);
            acc[0][1] = __builtin_amdgcn_mfma_f32_16x16x32_bf16(a0, b1, acc[0][1], 0, 0, 0);
            acc[1][0] = __builtin_amdgcn_mfma_f32_16x16x32_bf16(a1, b0, acc[1][0], 0, 0, 0);
            acc[1][1] = __builtin_amdgcn_mfma_f32_16x16x32_bf16(a1, b1, acc[1][1], 0, 0, 0);
        }
        // add X (bias already folded in) and dump to LDS
        const float* Xt = XT + (size_t)t * G4 * 64;
#pragma unroll
        for (int ni = 0; ni < 2; ++ni) {
            const int n_loc = wn + ni * 16 + fr;                 // 0..63
            const size_t grow = (size_t)((n_loc >> 4) * DD + j * 16 + fr) * 64;
#pragma unroll
            for (int mi = 0; mi < 2; ++mi) {
                const int b0r = wm + mi * 16 + fq * 4;
                const float4 xv = *(const float4*)(Xt + grow + b0r);
                gl[n_loc][b0r + 0] = acc[mi][ni][0] + xv.x;
                gl[n_loc][b0r + 1] = acc[mi][ni][1] + xv.y;
                gl[n_loc][b0r + 2] = acc[mi][ni][2] + xv.z;
                gl[n_loc][b0r + 3] = acc[mi][ni][3] + xv.w;
            }
        }
        __syncthreads();
        // epilogue: 1024 (dl,b) items over 256 threads
#pragma unroll
        for (int it = 0; it < 4; ++it) {
            const int idx = it * 256 + tid;
            const int dl = idx & 15;
            const int b = idx >> 4;
            const float i_ = 1.0f / (1.0f + expf(-gl[dl][b]));
            const float f_ = 1.0f / (1.0f + expf(-gl[16 + dl][b]));
            const float g_ = tanhf(gl[32 + dl][b]);
            const float o_ = 1.0f / (1.0f + expf(-gl[48 + dl][b]));
            const float cold = c_s[dl][b];
            const float cnew = f_ * cold + i_ * g_;
            const float hnew = o_ * tanhf(cnew);
            const bool act = t < dlen_s[b];
            const int d = j * 16 + dl;
            const unsigned short hold_u = ((const unsigned short*)Hp)[(size_t)b * DD + d];
            const unsigned short hu = act ? f2bf(hnew) : hold_u;
            ((unsigned short*)Hn)[(size_t)b * DD + d] = hu;
            hall[((size_t)b * TT + t) * DD + d] = hu;
            c_s[dl][b] = act ? cnew : cold;
        }
        grid_barrier(bcnt, bgen, NBLK);  // entry __syncthreads also fences gl reuse
    }
}

// ---------------- Kernel 5: bf16 MFMA FC head: out = hall @ Wfc^T + b_fc -------
// M = 8192 (row r = b*128+t), N = 10000 (guarded), K = 1024. m97 structure.
#define FBM 128
#define FBN 128
#define FBK 64

__global__ __launch_bounds__(256) void gemm_fc_mfma(const __bf16* __restrict__ A,
                                                    const __bf16* __restrict__ Bw,
                                                    const float* __restrict__ bfc,
                                                    float* __restrict__ out) {
    __shared__ __align__(16) __bf16 As[FBM * FBK];
    __shared__ __align__(16) __bf16 Bs[FBN * FBK];
    const int tid = threadIdx.x;
    const int lane = tid & 63;
    const int wave = tid >> 6;
    const int m0 = blockIdx.y * FBM;
    const int n0 = blockIdx.x * FBN;
    const int wm = (wave & 1) * 64;
    const int wn = (wave >> 1) * 64;
    const int fr = lane & 15;
    const int fq = lane >> 4;
    f32x4 acc[4][4] = {};
    for (int k0 = 0; k0 < DD; k0 += FBK) {
        __syncthreads();
#pragma unroll
        for (int i = 0; i < 4; ++i) {
            const int e = tid * 8 + i * 2048;
            const int row = e >> 6, col = e & 63;
            gload_lds16(A + (size_t)(m0 + row) * DD + k0 + col, &As[e]);
            int bn = n0 + row; if (bn >= VV) bn = VV - 1;
            gload_lds16(Bw + (size_t)bn * DD + k0 + col, &Bs[e]);
        }
        __syncthreads();
#pragma unroll
        for (int ks = 0; ks < 2; ++ks) {
            bf16x8 af[4], bfg[4];
#pragma unroll
            for (int mi = 0; mi < 4; ++mi)
                af[mi] = *(const bf16x8*)&As[(wm + mi * 16 + fr) * FBK + ks * 32 + fq * 8];
#pragma unroll
            for (int ni = 0; ni < 4; ++ni)
                bfg[ni] = *(const bf16x8*)&Bs[(wn + ni * 16 + fr) * FBK + ks * 32 + fq * 8];
#pragma unroll
            for (int mi = 0; mi < 4; ++mi)
#pragma unroll
                for (int ni = 0; ni < 4; ++ni)
                    acc[mi][ni] = __builtin_amdgcn_mfma_f32_16x16x32_bf16(
                        af[mi], bfg[ni], acc[mi][ni], 0, 0, 0);
        }
    }
#pragma unroll
    for (int mi = 0; mi < 4; ++mi)
#pragma unroll
        for (int ni = 0; ni < 4; ++ni) {
            const int col = n0 + wn + ni * 16 + fr;
            if (col < VV) {
                const float bias = bfc[col];
#pragma unroll
                for (int rg = 0; rg < 4; ++rg) {
                    const int row = m0 + wm + mi * 16 + fq * 4 + rg;
                    out[(size_t)row * VV + col] = acc[mi][ni][rg] + bias;
                }
            }
        }
}

// ---------------- launch ----------------
extern "C" void kernel_launch(void* const* d_in, const int* in_sizes, int n_in,
                              void* d_out, int out_size, void* d_ws, size_t ws_size,
                              hipStream_t stream) {
    const float* enc = (const float*)d_in[0];
    const int* capl = (const int*)d_in[1];
    const float* Wih = (const float*)d_in[2];
    const float* bih = (const float*)d_in[3];
    const float* Whh = (const float*)d_in[4];
    const float* bhh = (const float*)d_in[5];
    const float* Wfc = (const float*)d_in[6];
    const float* bfc = (const float*)d_in[7];
    float* out = (float*)d_out;

    char* ws = (char*)d_ws;
    int* sind = (int*)(ws + 0);
    int* declen = (int*)(ws + 256);
    int* bar = (int*)(ws + 512);                                   // cnt, gen
    __bf16* H0 = (__bf16*)(ws + 1024);                             // 128 KB
    __bf16* H1 = (__bf16*)(ws + 1024 + 131072);                    // 128 KB
    float* XT = (float*)(ws + 1024 + 262144);                      // 134.2 MB
    unsigned short* hallb = (unsigned short*)((char*)XT + (size_t)TT * BB * G4 * 4);  // 16.8 MB
    unsigned short* wfcb = hallb + (size_t)BB * TT * DD;           // 20.5 MB
    unsigned short* whhb = wfcb + (size_t)VV * DD;                 // 8.4 MB

    hipMemsetAsync(bar, 0, 8, stream);
    hipMemsetAsync(H0, 0, 262144, stream);  // both H buffers (contiguous)

    sort_kernel<<<1, 1, 0, stream>>>(capl, sind, declen);
    cvt_bf16<<<(VV * DD) / 1024, 256, 0, stream>>>(Wfc, wfcb, VV * DD);
    cvt_bf16<<<(4 * DD * DD) / 1024, 256, 0, stream>>>(Whh, whhb, 4 * DD * DD);

    gemm_x<<<dim3(G4 / TN, (BB * TT) / TM), 256, 0, stream>>>(enc, Wih, bih, bhh, sind, XT);

    recurrence<<<NBLK, 256, 0, stream>>>((const __bf16*)whhb, XT, declen, H0, H1,
                                         hallb, bar, bar + 1);

    gemm_fc_mfma<<<dim3((VV + FBN - 1) / FBN, (BB * TT) / FBM), 256, 0, stream>>>(
        (const __bf16*)hallb, (const __bf16*)wfcb, bfc, out);
}

// Round 8
// 2850.232 us; speedup vs baseline: 6.2189x; 1.6807x over previous
//
#include <hip/hip_runtime.h>
#include <math.h>

#define BB 64
#define TT 128
#define EE 1024
#define DD 1024
#define VV 10000
#define G4 4096  // 4*D
#define NBLK 64  // recurrence workgroups (all co-resident)

typedef float f32x4 __attribute__((ext_vector_type(4)));
typedef __bf16 bf16x8 __attribute__((ext_vector_type(8)));

__device__ __forceinline__ unsigned short f2bf(float f) {
    unsigned int u = __float_as_uint(f);
    return (unsigned short)((u + 0x7fffu + ((u >> 16) & 1u)) >> 16);  // RNE
}
__device__ __forceinline__ float b2f(unsigned short u) {
    return __uint_as_float(((unsigned int)u) << 16);
}

__device__ __forceinline__ void gload_lds16(const void* g, void* l) {
    __builtin_amdgcn_global_load_lds((const __attribute__((address_space(1))) void*)g,
                                     (__attribute__((address_space(3))) void*)l, 16, 0, 0);
}

// ---------------- Kernel 1: stable descending argsort of lengths ----------------
__global__ void sort_kernel(const int* __restrict__ lens_raw,
                            int* __restrict__ sort_ind,
                            int* __restrict__ dec_len) {
    // single thread; 64 elements. int64-vs-int32 autodetect: lens in [2,128],
    // so if buffer is int64 LE, word 1 (high word of lens[0]) is 0.
    int stride = (lens_raw[1] == 0) ? 2 : 1;
    int lens[BB], idx[BB];
    for (int i = 0; i < BB; ++i) { lens[i] = lens_raw[i * stride]; idx[i] = i; }
    for (int i = 1; i < BB; ++i) {  // stable insertion sort, descending
        int kl = lens[i], ki = idx[i];
        int j = i - 1;
        while (j >= 0 && lens[j] < kl) { lens[j+1] = lens[j]; idx[j+1] = idx[j]; --j; }
        lens[j+1] = kl; idx[j+1] = ki;
    }
    for (int i = 0; i < BB; ++i) { sort_ind[i] = idx[i]; dec_len[i] = lens[i] - 1; }
}

// ---------------- Kernel 2: f32 -> bf16 convert ----------------
__global__ __launch_bounds__(256) void cvt_bf16(const float* __restrict__ w,
                                                unsigned short* __restrict__ o, int n) {
    const int i = (blockIdx.x * 256 + threadIdx.x) * 4;
    if (i + 3 < n) {
        float4 v = *(const float4*)(w + i);
        ushort4 r;
        r.x = f2bf(v.x); r.y = f2bf(v.y); r.z = f2bf(v.z); r.w = f2bf(v.w);
        *(ushort4*)(o + i) = r;
    }
}

// ---------------- Kernel 3: bf16 MFMA GEMM  XT = (Wih @ enc_sorted^T) + bias ----
// Role-swapped so XT stores are coalesced: A = Wih rows (gate m, M=4096),
// B = enc rows (r = t*64+b, N=8192, gathered via sort_ind), K = 1024.
// XT stored bf16 as XT[(t*4096 + gate)*64 + b].
#define FBM 128
#define FBN 128
#define FBK 64

__global__ __launch_bounds__(256) void gemm_x_mfma(const __bf16* __restrict__ Wb,
                                                   const __bf16* __restrict__ Eb,
                                                   const float* __restrict__ bih,
                                                   const float* __restrict__ bhh,
                                                   const int* __restrict__ sind,
                                                   unsigned short* __restrict__ XT) {
    __shared__ __align__(16) __bf16 As[FBM * FBK];
    __shared__ __align__(16) __bf16 Bs[FBN * FBK];
    __shared__ int sind_s[BB];
    const int tid = threadIdx.x;
    if (tid < BB) sind_s[tid] = sind[tid];
    const int lane = tid & 63;
    const int wave = tid >> 6;
    const int m0 = blockIdx.y * FBM;   // gate dim
    const int n0 = blockIdx.x * FBN;   // r dim
    const int wm = (wave & 1) * 64;
    const int wn = (wave >> 1) * 64;
    const int fr = lane & 15;
    const int fq = lane >> 4;
    f32x4 acc[4][4] = {};
    for (int k0 = 0; k0 < EE; k0 += FBK) {
        __syncthreads();
#pragma unroll
        for (int i = 0; i < 4; ++i) {
            const int e = tid * 8 + i * 2048;
            const int row = e >> 6, col = e & 63;
            gload_lds16(Wb + (size_t)(m0 + row) * EE + k0 + col, &As[e]);
            const int gr = n0 + row, t = gr >> 6, b = gr & 63;
            gload_lds16(Eb + ((size_t)sind_s[b] * TT + t) * EE + k0 + col, &Bs[e]);
        }
        __syncthreads();
#pragma unroll
        for (int ks = 0; ks < 2; ++ks) {
            bf16x8 af[4], bfg[4];
#pragma unroll
            for (int mi = 0; mi < 4; ++mi)
                af[mi] = *(const bf16x8*)&As[(wm + mi * 16 + fr) * FBK + ks * 32 + fq * 8];
#pragma unroll
            for (int ni = 0; ni < 4; ++ni)
                bfg[ni] = *(const bf16x8*)&Bs[(wn + ni * 16 + fr) * FBK + ks * 32 + fq * 8];
#pragma unroll
            for (int mi = 0; mi < 4; ++mi)
#pragma unroll
                for (int ni = 0; ni < 4; ++ni)
                    acc[mi][ni] = __builtin_amdgcn_mfma_f32_16x16x32_bf16(
                        af[mi], bfg[ni], acc[mi][ni], 0, 0, 0);
        }
    }
    // D layout: col(=r) = lane&15 within ni-block, row(=gate) = fq*4+rg within mi-block
#pragma unroll
    for (int mi = 0; mi < 4; ++mi)
#pragma unroll
        for (int ni = 0; ni < 4; ++ni) {
            const int col = n0 + wn + ni * 16 + fr;   // r = t*64 + b
            const int t = col >> 6, b = col & 63;
#pragma unroll
            for (int rg = 0; rg < 4; ++rg) {
                const int row = m0 + wm + mi * 16 + fq * 4 + rg;  // gate
                XT[((size_t)t * G4 + row) * 64 + b] =
                    f2bf(acc[mi][ni][rg] + bih[row] + bhh[row]);
            }
        }
}

// ---------------- Kernel 4: persistent fused LSTM recurrence --------------------
// 64 blocks x 256 threads; block j owns d-slice [j*16, j*16+16) -> 64 gate rows.
// W_hh slice lives in LDS (128 KB, XOR-swizzled vs 16-way bank conflict).
// Per step: MFMA GEMV from LDS(W) x global(h, L2), += XT (bf16, prefetched
// under the barrier spin), gate math (c in LDS), write h (dbuf) + hall,
// parallel-flag grid barrier (64 flags on separate cachelines).
__global__ __launch_bounds__(256) void recurrence(const __bf16* __restrict__ Whhb,
                                                  const unsigned short* __restrict__ XT,
                                                  const int* __restrict__ declen,
                                                  __bf16* __restrict__ H0,
                                                  __bf16* __restrict__ H1,
                                                  unsigned short* __restrict__ hall,
                                                  int* __restrict__ flags) {
    __shared__ __align__(16) __bf16 Ws[64 * 1024];   // 128 KB swizzled W slice
    __shared__ float gl[64][65];     // [n_local][b] gate pre-activations
    __shared__ float c_s[16][65];    // [dl][b] cell state
    __shared__ int dlen_s[BB];
    const int tid = threadIdx.x;
    const int j = blockIdx.x;
    const int lane = tid & 63;
    const int wave = tid >> 6;
    const int wm = (wave & 1) * 32;   // batch sub-range
    const int wn = (wave >> 1) * 32;  // gate-row sub-range
    const int fr = lane & 15;
    const int fq = lane >> 4;

    // stage W slice into LDS, swizzled: byte = row*2048 + ((sl*16) ^ ((row&7)<<4))
    for (int ci = tid; ci < 8192; ci += 256) {
        const int row = ci >> 7;       // local row 0..63 (= g*16 + dl)
        const int sl = ci & 127;       // 16B slot within row
        const int grow = (row >> 4) * DD + j * 16 + (row & 15);
        bf16x8 v = *(const bf16x8*)(Whhb + (size_t)grow * DD + sl * 8);
        *(bf16x8*)((char*)Ws + row * 2048 + ((sl * 16) ^ ((row & 7) << 4))) = v;
    }
    if (tid < BB) dlen_s[tid] = declen[tid];
    for (int i = tid; i < 16 * 65; i += 256) (&c_s[0][0])[i] = 0.f;
    __syncthreads();

    const int g0 = wn >> 4;                       // first gate block (0..3)
    const int rl0 = (g0 + 0) * 16 + fr;           // local W rows
    const int rl1 = (g0 + 1) * 16 + fr;
    const int sw0 = (rl0 & 7) << 4;               // rl1&7 == rl0&7
    const char* Wc = (const char*)Ws;
    const size_t grow0 = (size_t)((g0 + 0) * DD + j * 16 + fr) * 64;
    const size_t grow1 = (size_t)((g0 + 1) * DD + j * 16 + fr) * 64;
    const int b0r0 = wm + fq * 4;
    const int b0r1 = wm + 16 + fq * 4;

    ushort4 xv00, xv01, xv10, xv11;  // xv{ni}{mi}
#define LOAD_XT(tt) do { \
        const unsigned short* Xt_ = XT + (size_t)(tt) * G4 * 64; \
        xv00 = *(const ushort4*)(Xt_ + grow0 + b0r0); \
        xv01 = *(const ushort4*)(Xt_ + grow0 + b0r1); \
        xv10 = *(const ushort4*)(Xt_ + grow1 + b0r0); \
        xv11 = *(const ushort4*)(Xt_ + grow1 + b0r1); \
    } while (0)

    LOAD_XT(0);
    for (int t = 0; t < TT; ++t) {
        const __bf16* Hp = (t & 1) ? H1 : H0;
        __bf16* Hn = (t & 1) ? H0 : H1;
        const __bf16* arow0 = Hp + (size_t)(wm + fr) * DD;
        const __bf16* arow1 = Hp + (size_t)(wm + 16 + fr) * DD;
        f32x4 acc[2][2] = {};
#pragma unroll 4
        for (int k0 = 0; k0 < DD; k0 += 32) {
            const int ko = k0 + fq * 8;
            const int off = ko * 2;
            bf16x8 a0 = *(const bf16x8*)(arow0 + ko);
            bf16x8 a1 = *(const bf16x8*)(arow1 + ko);
            bf16x8 b0 = *(const bf16x8*)(Wc + rl0 * 2048 + (off ^ sw0));
            bf16x8 b1 = *(const bf16x8*)(Wc + rl1 * 2048 + (off ^ sw0));
            acc[0][0] = __builtin_amdgcn_mfma_f32_16x16x32_bf16(a0, b0, acc[0][0], 0, 0, 0);
            acc[0][1] = __builtin_amdgcn_mfma_f32_16x16x32_bf16(a0, b1, acc[0][1], 0, 0, 0);
            acc[1][0] = __builtin_amdgcn_mfma_f32_16x16x32_bf16(a1, b0, acc[1][0], 0, 0, 0);
            acc[1][1] = __builtin_amdgcn_mfma_f32_16x16x32_bf16(a1, b1, acc[1][1], 0, 0, 0);
        }
        // add X and dump to LDS. acc[mi][ni]; xv{ni}{mi}.
        {
            const int n0l = wn + fr, n1l = wn + 16 + fr;
            gl[n0l][b0r0 + 0] = acc[0][0][0] + b2f(xv00.x);
            gl[n0l][b0r0 + 1] = acc[0][0][1] + b2f(xv00.y);
            gl[n0l][b0r0 + 2] = acc[0][0][2] + b2f(xv00.z);
            gl[n0l][b0r0 + 3] = acc[0][0][3] + b2f(xv00.w);
            gl[n0l][b0r1 + 0] = acc[1][0][0] + b2f(xv01.x);
            gl[n0l][b0r1 + 1] = acc[1][0][1] + b2f(xv01.y);
            gl[n0l][b0r1 + 2] = acc[1][0][2] + b2f(xv01.z);
            gl[n0l][b0r1 + 3] = acc[1][0][3] + b2f(xv01.w);
            gl[n1l][b0r0 + 0] = acc[0][1][0] + b2f(xv10.x);
            gl[n1l][b0r0 + 1] = acc[0][1][1] + b2f(xv10.y);
            gl[n1l][b0r0 + 2] = acc[0][1][2] + b2f(xv10.z);
            gl[n1l][b0r0 + 3] = acc[0][1][3] + b2f(xv10.w);
            gl[n1l][b0r1 + 0] = acc[1][1][0] + b2f(xv11.x);
            gl[n1l][b0r1 + 1] = acc[1][1][1] + b2f(xv11.y);
            gl[n1l][b0r1 + 2] = acc[1][1][2] + b2f(xv11.z);
            gl[n1l][b0r1 + 3] = acc[1][1][3] + b2f(xv11.w);
        }
        __syncthreads();
        // epilogue: 1024 (dl,b) items over 256 threads
#pragma unroll
        for (int it = 0; it < 4; ++it) {
            const int idx = it * 256 + tid;
            const int dl = idx & 15;
            const int b = idx >> 4;
            const float i_ = 1.0f / (1.0f + expf(-gl[dl][b]));
            const float f_ = 1.0f / (1.0f + expf(-gl[16 + dl][b]));
            const float g_ = tanhf(gl[32 + dl][b]);
            const float o_ = 1.0f / (1.0f + expf(-gl[48 + dl][b]));
            const float cold = c_s[dl][b];
            const float cnew = f_ * cold + i_ * g_;
            const float hnew = o_ * tanhf(cnew);
            const bool act = t < dlen_s[b];
            const int d = j * 16 + dl;
            const unsigned short hold_u = ((const unsigned short*)Hp)[(size_t)b * DD + d];
            const unsigned short hu = act ? f2bf(hnew) : hold_u;
            ((unsigned short*)Hn)[(size_t)b * DD + d] = hu;
            hall[((size_t)b * TT + t) * DD + d] = hu;
            c_s[dl][b] = act ? cnew : cold;
        }
        if (t + 1 < TT) {
            // parallel-flag grid barrier; XT prefetch hides under the spin
            __syncthreads();
            if (tid == 0) {
                __threadfence();
                __hip_atomic_store(flags + j * 32, t + 1, __ATOMIC_RELEASE,
                                   __HIP_MEMORY_SCOPE_AGENT);
            }
            LOAD_XT(t + 1);
            if (tid < NBLK) {
                while (__hip_atomic_load(flags + tid * 32, __ATOMIC_ACQUIRE,
                                         __HIP_MEMORY_SCOPE_AGENT) < t + 1) {}
            }
            __syncthreads();
        }
    }
}

// ---------------- Kernel 5: bf16 MFMA FC head: out = hall @ Wfc^T + b_fc -------
// M = 8192 (row r = b*128+t), N = 10000 (guarded), K = 1024. m97 structure.
__global__ __launch_bounds__(256) void gemm_fc_mfma(const __bf16* __restrict__ A,
                                                    const __bf16* __restrict__ Bw,
                                                    const float* __restrict__ bfc,
                                                    float* __restrict__ out) {
    __shared__ __align__(16) __bf16 As[FBM * FBK];
    __shared__ __align__(16) __bf16 Bs[FBN * FBK];
    const int tid = threadIdx.x;
    const int lane = tid & 63;
    const int wave = tid >> 6;
    const int m0 = blockIdx.y * FBM;
    const int n0 = blockIdx.x * FBN;
    const int wm = (wave & 1) * 64;
    const int wn = (wave >> 1) * 64;
    const int fr = lane & 15;
    const int fq = lane >> 4;
    f32x4 acc[4][4] = {};
    for (int k0 = 0; k0 < DD; k0 += FBK) {
        __syncthreads();
#pragma unroll
        for (int i = 0; i < 4; ++i) {
            const int e = tid * 8 + i * 2048;
            const int row = e >> 6, col = e & 63;
            gload_lds16(A + (size_t)(m0 + row) * DD + k0 + col, &As[e]);
            int bn = n0 + row; if (bn >= VV) bn = VV - 1;
            gload_lds16(Bw + (size_t)bn * DD + k0 + col, &Bs[e]);
        }
        __syncthreads();
#pragma unroll
        for (int ks = 0; ks < 2; ++ks) {
            bf16x8 af[4], bfg[4];
#pragma unroll
            for (int mi = 0; mi < 4; ++mi)
                af[mi] = *(const bf16x8*)&As[(wm + mi * 16 + fr) * FBK + ks * 32 + fq * 8];
#pragma unroll
            for (int ni = 0; ni < 4; ++ni)
                bfg[ni] = *(const bf16x8*)&Bs[(wn + ni * 16 + fr) * FBK + ks * 32 + fq * 8];
#pragma unroll
            for (int mi = 0; mi < 4; ++mi)
#pragma unroll
                for (int ni = 0; ni < 4; ++ni)
                    acc[mi][ni] = __builtin_amdgcn_mfma_f32_16x16x32_bf16(
                        af[mi], bfg[ni], acc[mi][ni], 0, 0, 0);
        }
    }
#pragma unroll
    for (int mi = 0; mi < 4; ++mi)
#pragma unroll
        for (int ni = 0; ni < 4; ++ni) {
            const int col = n0 + wn + ni * 16 + fr;
            if (col < VV) {
                const float bias = bfc[col];
#pragma unroll
                for (int rg = 0; rg < 4; ++rg) {
                    const int row = m0 + wm + mi * 16 + fq * 4 + rg;
                    out[(size_t)row * VV + col] = acc[mi][ni][rg] + bias;
                }
            }
        }
}

// ---------------- launch ----------------
extern "C" void kernel_launch(void* const* d_in, const int* in_sizes, int n_in,
                              void* d_out, int out_size, void* d_ws, size_t ws_size,
                              hipStream_t stream) {
    const float* enc = (const float*)d_in[0];
    const int* capl = (const int*)d_in[1];
    const float* Wih = (const float*)d_in[2];
    const float* bih = (const float*)d_in[3];
    const float* Whh = (const float*)d_in[4];
    const float* bhh = (const float*)d_in[5];
    const float* Wfc = (const float*)d_in[6];
    const float* bfc = (const float*)d_in[7];
    float* out = (float*)d_out;

    char* ws = (char*)d_ws;
    int* sind = (int*)(ws + 0);
    int* declen = (int*)(ws + 256);
    int* flags = (int*)(ws + 512);                                  // 64 x 128B
    __bf16* H0 = (__bf16*)(ws + 16384);                             // 128 KB
    __bf16* H1 = (__bf16*)(ws + 16384 + 131072);                    // 128 KB
    unsigned short* XTb = (unsigned short*)(ws + 16384 + 262144);   // 67.1 MB
    unsigned short* hallb = XTb + (size_t)TT * G4 * 64;             // 16.8 MB
    unsigned short* wfcb = hallb + (size_t)BB * TT * DD;            // 20.5 MB
    unsigned short* whhb = wfcb + (size_t)VV * DD;                  // 8.4 MB
    unsigned short* wihb = whhb + (size_t)G4 * DD;                  // 8.4 MB
    unsigned short* encb = wihb + (size_t)G4 * EE;                  // 16.8 MB

    hipMemsetAsync(flags, 0, 8192, stream);
    hipMemsetAsync(H0, 0, 262144, stream);  // both H buffers (contiguous)

    sort_kernel<<<1, 1, 0, stream>>>(capl, sind, declen);
    cvt_bf16<<<(VV * DD) / 1024, 256, 0, stream>>>(Wfc, wfcb, VV * DD);
    cvt_bf16<<<(G4 * DD) / 1024, 256, 0, stream>>>(Whh, whhb, G4 * DD);
    cvt_bf16<<<(G4 * EE) / 1024, 256, 0, stream>>>(Wih, wihb, G4 * EE);
    cvt_bf16<<<(BB * TT * EE) / 1024, 256, 0, stream>>>(enc, encb, BB * TT * EE);

    gemm_x_mfma<<<dim3((BB * TT) / FBN, G4 / FBM), 256, 0, stream>>>(
        (const __bf16*)wihb, (const __bf16*)encb, bih, bhh, sind, XTb);

    recurrence<<<NBLK, 256, 0, stream>>>((const __bf16*)whhb, XTb, declen, H0, H1,
                                         hallb, flags);

    gemm_fc_mfma<<<dim3((VV + FBN - 1) / FBN, (BB * TT) / FBM), 256, 0, stream>>>(
        (const __bf16*)hallb, (const __bf16*)wfcb, bfc, out);
}